// Round 8
// baseline (211.199 us; speedup 1.0000x reference)
//
#include <hip/hip_runtime.h>
#include <hip/hip_cooperative_groups.h>

namespace cg = cooperative_groups;

// x: (B, T+1, T) fp32.  pad = x[:,0,:], sig = x[:,1:,:]
// s[t] = sum_i |sig[i,t]|; w = sigmoid(pad - s)
// out[:,0,:] = w*pad; out[:,1+i,:] = (1-w[i])*sig[i,:]
//
// Cooperative single-kernel, grid-stride over 1024 chunks (chunk = 32 rows
// of one batch):
//  Phase 1: stream own rows (dense 256KB contiguous read) -> partial colsums
//           ws[chunk][2048].
//  grid sync
//  Phase 2: reduce 64 per-batch partials at own 32 columns -> w; write row-0
//           slice; scale+NT-write the SAME rows read in phase 1 (L3-warm).
// Grid size comes from the occupancy API (R7's hard-coded 1024 was rejected
// by the cooperative-launch validator); grid-stride keeps any size correct.
// If cooperative launch is rejected, fall back to the two-kernel split.

#define TDIM 2048
#define BDIM 16
#define ROWS 32
#define NTHREADS 512
#define NCHUNK (BDIM * (TDIM / ROWS))   // 1024

typedef float floatx4 __attribute__((ext_vector_type(4)));

__global__ __launch_bounds__(NTHREADS, 8) void pb_coop(const float* __restrict__ x,
                                                       float* __restrict__ ws,
                                                       float* __restrict__ out,
                                                       int nblk) {
    const int t = threadIdx.x;
    const size_t plane = (size_t)(TDIM + 1) * TDIM;

    // ---- Phase 1: per-chunk partial colsums (row-contiguous streaming) ----
    for (int c = blockIdx.x; c < NCHUNK; c += nblk) {
        const int b  = c >> 6;
        const int r0 = (c & 63) * ROWS;
        const float* src = x + (size_t)b * plane + TDIM + (size_t)r0 * TDIM + 4 * t;
        float a0 = 0.f, a1 = 0.f, a2 = 0.f, a3 = 0.f;
        #pragma unroll 8
        for (int r = 0; r < ROWS; ++r) {          // one full 8KB row per iter
            const floatx4 v = *reinterpret_cast<const floatx4*>(src + (size_t)r * TDIM);
            a0 += fabsf(v.x); a1 += fabsf(v.y); a2 += fabsf(v.z); a3 += fabsf(v.w);
        }
        floatx4 p4; p4.x = a0; p4.y = a1; p4.z = a2; p4.w = a3;
        *reinterpret_cast<floatx4*>(ws + (size_t)c * TDIM + 4 * t) = p4;
    }

    cg::this_grid().sync();

    // ---- Phase 2: reduce partials -> w; scale + NT-write own rows ----
    __shared__ float red[16][ROWS];
    __shared__ float lds_scale[ROWS];
    const int cc = t & 31;                        // column within stripe
    const int jg = t >> 5;                        // 0..15, covers 4 partials
    for (int c = blockIdx.x; c < NCHUNK; c += nblk) {
        const int b  = c >> 6;
        const int r0 = (c & 63) * ROWS;
        const float* xb = x   + (size_t)b * plane;
        float*       ob = out + (size_t)b * plane;

        float s = 0.f;
        #pragma unroll
        for (int j = 0; j < 4; ++j)
            s += ws[(size_t)(b * 64 + jg * 4 + j) * TDIM + r0 + cc];
        red[jg][cc] = s;
        __syncthreads();

        if (t < ROWS) {
            float tot = 0.f;
            #pragma unroll
            for (int j = 0; j < 16; ++j) tot += red[j][t];
            const float p = xb[r0 + t];                    // pad[r0+t]
            const float w = 1.0f / (1.0f + expf(tot - p)); // sigmoid(p - tot)
            ob[r0 + t]    = w * p;                         // out row 0 slice
            lds_scale[t]  = 1.0f - w;
        }
        __syncthreads();

        const float* srcb = xb + TDIM + (size_t)r0 * TDIM;
        float*       dstb = ob + TDIM + (size_t)r0 * TDIM;
        #pragma unroll 4
        for (int r = 0; r < ROWS; ++r) {
            floatx4 v = *reinterpret_cast<const floatx4*>(srcb + (size_t)r * TDIM + 4 * t);
            const float sc = lds_scale[r];
            v.x *= sc; v.y *= sc; v.z *= sc; v.w *= sc;
            __builtin_nontemporal_store(v, reinterpret_cast<floatx4*>(dstb + (size_t)r * TDIM + 4 * t));
        }
        // no trailing sync needed: red/lds_scale of the next chunk are only
        // overwritten after barriers that require all threads to finish here.
    }
}

// ---- Fallback path (non-cooperative), proven correct in R6 ----
__global__ __launch_bounds__(NTHREADS, 8) void colsum_kernel(const float* __restrict__ x,
                                                             float* __restrict__ ws) {
    const int k  = blockIdx.x;
    const int b  = k >> 6;
    const int r0 = (k & 63) * ROWS;
    const int t  = threadIdx.x;
    const size_t plane = (size_t)(TDIM + 1) * TDIM;
    const float* src = x + (size_t)b * plane + TDIM + (size_t)r0 * TDIM + 4 * t;
    float a0 = 0.f, a1 = 0.f, a2 = 0.f, a3 = 0.f;
    #pragma unroll 8
    for (int r = 0; r < ROWS; ++r) {
        const floatx4 v = *reinterpret_cast<const floatx4*>(src + (size_t)r * TDIM);
        a0 += fabsf(v.x); a1 += fabsf(v.y); a2 += fabsf(v.z); a3 += fabsf(v.w);
    }
    floatx4 p4; p4.x = a0; p4.y = a1; p4.z = a2; p4.w = a3;
    *reinterpret_cast<floatx4*>(ws + (size_t)k * TDIM + 4 * t) = p4;
}

__global__ __launch_bounds__(NTHREADS, 8) void scale_kernel(const float* __restrict__ x,
                                                            const float* __restrict__ ws,
                                                            float* __restrict__ out) {
    const int k  = NCHUNK - 1 - blockIdx.x;
    const int b  = k >> 6;
    const int r0 = (k & 63) * ROWS;
    const int t  = threadIdx.x;
    const size_t plane = (size_t)(TDIM + 1) * TDIM;
    const float* xb  = x   + (size_t)b * plane;
    float*       ob  = out + (size_t)b * plane;

    __shared__ float red[16][ROWS];
    __shared__ float lds_scale[ROWS];
    const int cc = t & 31;
    const int jg = t >> 5;
    float s = 0.f;
    #pragma unroll
    for (int j = 0; j < 4; ++j)
        s += ws[(size_t)(b * 64 + jg * 4 + j) * TDIM + r0 + cc];
    red[jg][cc] = s;
    __syncthreads();

    if (t < ROWS) {
        float tot = 0.f;
        #pragma unroll
        for (int j = 0; j < 16; ++j) tot += red[j][t];
        const float p = xb[r0 + t];
        const float w = 1.0f / (1.0f + expf(tot - p));
        ob[r0 + t]    = w * p;
        lds_scale[t]  = 1.0f - w;
    }
    __syncthreads();

    const float* srcb = xb + TDIM + (size_t)r0 * TDIM;
    float*       dstb = ob + TDIM + (size_t)r0 * TDIM;
    #pragma unroll 4
    for (int r = 0; r < ROWS; ++r) {
        floatx4 v = *reinterpret_cast<const floatx4*>(srcb + (size_t)r * TDIM + 4 * t);
        const float sc = lds_scale[r];
        v.x *= sc; v.y *= sc; v.z *= sc; v.w *= sc;
        __builtin_nontemporal_store(v, reinterpret_cast<floatx4*>(dstb + (size_t)r * TDIM + 4 * t));
    }
}

extern "C" void kernel_launch(void* const* d_in, const int* in_sizes, int n_in,
                              void* d_out, int out_size, void* d_ws, size_t ws_size,
                              hipStream_t stream) {
    const float* x   = (const float*)d_in[0];
    float*       out = (float*)d_out;
    float*       ws  = (float*)d_ws;   // 1024*2048*4 = 8 MB partial colsums

    // Size the cooperative grid from the occupancy API (deterministic query).
    int maxPerCU = 0;
    hipError_t qerr = hipOccupancyMaxActiveBlocksPerMultiprocessor(&maxPerCU, pb_coop,
                                                                   NTHREADS, 0);
    int nblk = (qerr == hipSuccess) ? maxPerCU * 256 : 0;   // MI355X: 256 CUs
    if (nblk > NCHUNK) nblk = NCHUNK;

    hipError_t lerr = hipErrorUnknown;
    if (nblk > 0) {
        void* args[] = { (void*)&x, (void*)&ws, (void*)&out, (void*)&nblk };
        lerr = hipLaunchCooperativeKernel(pb_coop, dim3(nblk), dim3(NTHREADS),
                                          args, 0, stream);
    }
    if (lerr != hipSuccess) {
        // Deterministic fallback (same decision every call on this runtime).
        colsum_kernel<<<NCHUNK, NTHREADS, 0, stream>>>(x, ws);
        scale_kernel <<<NCHUNK, NTHREADS, 0, stream>>>(x, ws, out);
    }
}

// Round 9
// 137.522 us; speedup vs baseline: 1.5357x; 1.5357x over previous
//
#include <hip/hip_runtime.h>

// x: (B, T+1, T) fp32.  pad = x[:,0,:], sig = x[:,1:,:]
// s[t] = sum_i |sig[i,t]|; w = sigmoid(pad - s)
// out[:,0,:] = w*pad; out[:,1+i,:] = (1-w[i])*sig[i,:]
//
// Two-kernel split with SEQUENCED K2:
//  K1: block k streams its 32 contiguous rows (256KB dense read) -> partial
//      colsum vector ws[k][2048] (plain stores, no atomics, no memset).
//  K2: 512 blocks, each handles 2 chunks in REVERSE K1-recency order
//      (iter 0 = the 512 most-recently-read chunks -> L3-hot; iter 1 = rest,
//      still resident because NT output stores don't allocate in L3 and only
//      ~12MB of cold misses filled in). Reduces 64 partials -> w, writes
//      row-0 slice, scale+NT-writes its 32 rows.

#define TDIM 2048
#define BDIM 16
#define ROWS 32
#define NTHREADS 512
#define NCHUNK (BDIM * (TDIM / ROWS))   // 1024
#define K2BLK 512
#define K2ITER (NCHUNK / K2BLK)          // 2

typedef float floatx4 __attribute__((ext_vector_type(4)));

__global__ __launch_bounds__(NTHREADS, 8) void colsum_kernel(const float* __restrict__ x,
                                                             float* __restrict__ ws) {
    const int k  = blockIdx.x;               // 0..1023
    const int b  = k >> 6;
    const int r0 = (k & 63) * ROWS;
    const int t  = threadIdx.x;
    const size_t plane = (size_t)(TDIM + 1) * TDIM;
    const float* src = x + (size_t)b * plane + TDIM + (size_t)r0 * TDIM + 4 * t;

    float a0 = 0.f, a1 = 0.f, a2 = 0.f, a3 = 0.f;
    #pragma unroll 8
    for (int r = 0; r < ROWS; ++r) {         // one full 8KB row per iter
        const floatx4 v = *reinterpret_cast<const floatx4*>(src + (size_t)r * TDIM);
        a0 += fabsf(v.x); a1 += fabsf(v.y); a2 += fabsf(v.z); a3 += fabsf(v.w);
    }
    floatx4 p4; p4.x = a0; p4.y = a1; p4.z = a2; p4.w = a3;
    *reinterpret_cast<floatx4*>(ws + (size_t)k * TDIM + 4 * t) = p4;
}

__global__ __launch_bounds__(NTHREADS, 8) void scale_kernel(const float* __restrict__ x,
                                                            const float* __restrict__ ws,
                                                            float* __restrict__ out) {
    const int j = blockIdx.x;                // 0..511
    const int t = threadIdx.x;
    const size_t plane = (size_t)(TDIM + 1) * TDIM;

    __shared__ float red[16][ROWS];
    __shared__ float lds_scale[ROWS];
    const int cc = t & 31;                   // column within stripe
    const int jg = t >> 5;                   // 0..15, each covers 4 partials

    for (int i = 0; i < K2ITER; ++i) {
        const int k  = NCHUNK - 1 - j - K2BLK * i;   // reverse-recency order
        const int b  = k >> 6;
        const int r0 = (k & 63) * ROWS;
        const float* xb = x   + (size_t)b * plane;
        float*       ob = out + (size_t)b * plane;

        float s = 0.f;
        #pragma unroll
        for (int q = 0; q < 4; ++q)
            s += ws[(size_t)(b * 64 + jg * 4 + q) * TDIM + r0 + cc];
        red[jg][cc] = s;
        __syncthreads();

        if (t < ROWS) {
            float tot = 0.f;
            #pragma unroll
            for (int q = 0; q < 16; ++q) tot += red[q][t];
            const float p = xb[r0 + t];                    // pad[r0+t]
            const float w = 1.0f / (1.0f + expf(tot - p)); // sigmoid(p - tot)
            ob[r0 + t]    = w * p;                         // out row 0 slice
            lds_scale[t]  = 1.0f - w;
        }
        __syncthreads();

        const float* srcb = xb + TDIM + (size_t)r0 * TDIM;
        float*       dstb = ob + TDIM + (size_t)r0 * TDIM;
        #pragma unroll 4
        for (int r = 0; r < ROWS; ++r) {
            floatx4 v = *reinterpret_cast<const floatx4*>(srcb + (size_t)r * TDIM + 4 * t);
            const float sc = lds_scale[r];
            v.x *= sc; v.y *= sc; v.z *= sc; v.w *= sc;
            __builtin_nontemporal_store(v, reinterpret_cast<floatx4*>(dstb + (size_t)r * TDIM + 4 * t));
        }
        __syncthreads();   // protect red[] overwrite vs slow readers next iter
    }
}

extern "C" void kernel_launch(void* const* d_in, const int* in_sizes, int n_in,
                              void* d_out, int out_size, void* d_ws, size_t ws_size,
                              hipStream_t stream) {
    const float* x   = (const float*)d_in[0];
    float*       out = (float*)d_out;
    float*       ws  = (float*)d_ws;   // 1024*2048*4 = 8 MB partial colsums

    colsum_kernel<<<NCHUNK, NTHREADS, 0, stream>>>(x, ws);
    scale_kernel <<<K2BLK,  NTHREADS, 0, stream>>>(x, ws, out);
}